// Round 6
// baseline (298.019 us; speedup 1.0000x reference)
//
#include <hip/hip_runtime.h>
#include <hip/hip_bf16.h>

#define D 256
#define TEMP_INV 20.0f   // 1 / 0.05
#define NJ 8             // 128-col tiles per colgroup (1024 cols per block)
#define NS (NJ * 8)      // K-steps per block (BK=32)

typedef __attribute__((ext_vector_type(8))) short bf16x8s;   // 8 bf16 in 4 VGPRs
typedef __attribute__((ext_vector_type(16))) float f32x16;   // 32x32 accum

// ---- helpers ----------------------------------------------------------------
__device__ __forceinline__ unsigned short f2bf(float f) {
  unsigned u = __float_as_uint(f);
  unsigned r = u + 0x7FFFu + ((u >> 16) & 1u);
  return (unsigned short)(r >> 16);
}

__device__ __forceinline__ void gld16(const void* g, void* l) {
  // async global->LDS, 16B/lane; LDS dest is wave-uniform base + lane*16
  __builtin_amdgcn_global_load_lds(
      (const __attribute__((address_space(1))) void*)g,
      (__attribute__((address_space(3))) void*)l, 16, 0, 0);
}

// ---- kernel 1: fused row L2-normalize f32 -> bf16 (3 inputs) + zero rowsum --
__global__ __launch_bounds__(256) void nce_normalize(const float* __restrict__ anc,
                                                     const float* __restrict__ pos,
                                                     const float* __restrict__ neg,
                                                     unsigned short* __restrict__ An,
                                                     unsigned short* __restrict__ Tn,
                                                     float* __restrict__ rowsum,
                                                     int B) {
  int zi = blockIdx.x * 256 + threadIdx.x;
  if (blockIdx.x < (B + 255) / 256 && zi < B) rowsum[zi] = 0.0f;

  const int lane = threadIdx.x & 63;
  const int wid  = threadIdx.x >> 6;
  const int sub  = lane >> 4, lr = lane & 15;
  int row = blockIdx.x * 16 + wid * 4 + sub;

  const float* src;
  unsigned short* dst;
  int r2;
  if (row < B)          { src = anc; dst = An; r2 = row; }
  else if (row < 2 * B) { src = pos; dst = Tn; r2 = row - B; }
  else                  { src = neg; dst = Tn + (size_t)B * D; r2 = row - 2 * B; }

  const float4* sp = reinterpret_cast<const float4*>(src) + (size_t)r2 * (D / 4);
  float4 v[4];
#pragma unroll
  for (int c = 0; c < 4; ++c) v[c] = sp[lr + c * 16];
  float ss = 0.0f;
#pragma unroll
  for (int c = 0; c < 4; ++c)
    ss += v[c].x * v[c].x + v[c].y * v[c].y + v[c].z * v[c].z + v[c].w * v[c].w;
  ss += __shfl_xor(ss, 1, 64);
  ss += __shfl_xor(ss, 2, 64);
  ss += __shfl_xor(ss, 4, 64);
  ss += __shfl_xor(ss, 8, 64);
  float inv = rsqrtf(fmaxf(ss, 1e-24f));
  ushort4* dp = reinterpret_cast<ushort4*>(dst) + (size_t)r2 * (D / 4);
#pragma unroll
  for (int c = 0; c < 4; ++c) {
    ushort4 o;
    o.x = f2bf(v[c].x * inv);
    o.y = f2bf(v[c].y * inv);
    o.z = f2bf(v[c].z * inv);
    o.w = f2bf(v[c].w * inv);
    dp[lr + c * 16] = o;
  }
}

// ---- kernel 2: A-in-registers 32x32x16 MFMA GEMM, prefetch pipeline ---------
// Block: 128 rows x 1024 cols (NJ=8 j-tiles of 128), K=256. 4 waves as 2x2,
// wave tile 64x64 = 2x2 of 32x32 frags. A panel in VGPRs (2x16 bf16x8 = 128).
// B streams through a 4-buffer LDS ring (4x8KB = 32KB). Swizzle: row R (64B,
// 4x16B chunks), stored chunk p' = p ^ ((R>>1)&3) -> quarter-wave reads land
// 2-way (free). Staged via global_load_lds w=16 with inverse-swizzled source.
// Per step s (= j*8+kt, all LDS indices compile-time via kt):
//   vmcnt(2) -> s_barrier -> STAGE(s+3) -> ds_read frags(s+1) -> lgkmcnt(4)
//   -> sched_barrier -> setprio(1) 8x MFMA(frags s) setprio(0)
// vmcnt BEFORE the barrier proves every wave's stage(s+1) landed before any
// wave reads it; STAGE(s+3) overwrites buf(s-1), whose readers drained at
// their step s-1 lgkmcnt(4) (ring 4, distance 3). Per-lane exp partials
// accumulate across j-tiles; single shuffle-reduce + atomics at block end.
__global__ __launch_bounds__(256, 4) void nce_scores(const unsigned short* __restrict__ A,
                                                     const unsigned short* __restrict__ T,
                                                     float* __restrict__ rowsum,
                                                     float* __restrict__ diag) {
  __shared__ unsigned char smem[4][8192];

  const int tid  = threadIdx.x;
  const int lane = tid & 63;
  const int wid  = __builtin_amdgcn_readfirstlane(tid >> 6);
  const int wr = wid >> 1, wc = wid & 1;
  const int row0 = blockIdx.y * 128;
  const int cg   = blockIdx.x;              // cols [cg*1024, +1024)
  const int r32 = lane & 31, g2 = lane >> 5;

  // ---- staging: lane i covers LDS row (i>>2), stored chunk i&3 ----
  // inverse swizzle: source chunk p = (i&3) ^ ((R>>1)&3) = (i&3) ^ ((i>>3)&3)
  const int Rl = lane >> 2;
  const int Cl = (lane & 3) ^ ((lane >> 3) & 3);
  const unsigned char* gB = (const unsigned char*)T +
      (((size_t)(cg * 1024 + wid * 32 + Rl)) << 9) + Cl * 16;

  auto STAGE = [&](int j2, int kt2, int buf) {
    const unsigned char* gb = gB + (size_t)j2 * 65536 + kt2 * 64;
    unsigned char* sb = &smem[buf][0];
    gld16(gb,        sb + wid * 2048);           // rows [wid*32, +16)
    gld16(gb + 8192, sb + wid * 2048 + 1024);    // rows [wid*32+16, +16)
  };

  // ---- read offsets: frag (s2,n): R = wc*64+n*32+r32, chunk (2s2+g2)^((r32>>1)&3)
  const int xr = (r32 >> 1) & 3;
  int offB[2][2];
#pragma unroll
  for (int s2 = 0; s2 < 2; ++s2)
#pragma unroll
    for (int n = 0; n < 2; ++n)
      offB[s2][n] = ((wc * 64 + n * 32 + r32) << 6) + ((((s2 << 1) | g2) ^ xr) << 4);

  // ---- A panel into registers: lane holds A[row0+wr*64+m*32+r32][ks*16+g2*8 ..+8]
  const unsigned short* aPtr = A + (size_t)(row0 + wr * 64 + r32) * D + g2 * 8;
  bf16x8s aF[2][16];
#pragma unroll
  for (int m = 0; m < 2; ++m)
#pragma unroll
    for (int ks = 0; ks < 16; ++ks)
      aF[m][ks] = *reinterpret_cast<const bf16x8s*>(aPtr + (size_t)m * 32 * D + ks * 16);

  float rs[2][16];
#pragma unroll
  for (int m = 0; m < 2; ++m)
#pragma unroll
    for (int reg = 0; reg < 16; ++reg) rs[m][reg] = 0.0f;

  bf16x8s bF[2][2][2];   // [regbuf][s2][n] — all indices compile-time

  // ---- prologue: 3 stages in flight; read frags(0) ----
  STAGE(0, 0, 0);
  STAGE(0, 1, 1);
  STAGE(0, 2, 2);
  asm volatile("s_waitcnt vmcnt(4)" ::: "memory");   // stage(0) landed (mine)
  __builtin_amdgcn_s_barrier();                       // landed for all waves
  {
    const unsigned char* sb0 = &smem[0][0];
#pragma unroll
    for (int s2 = 0; s2 < 2; ++s2)
#pragma unroll
      for (int n = 0; n < 2; ++n)
        bF[0][s2][n] = *reinterpret_cast<const bf16x8s*>(sb0 + offB[s2][n]);
  }

  for (int j = 0; j < NJ; ++j) {
    f32x16 acc[2][2];
#pragma unroll
    for (int m = 0; m < 2; ++m)
#pragma unroll
      for (int n = 0; n < 2; ++n) acc[m][n] = (f32x16)0.0f;

#pragma unroll
    for (int kt = 0; kt < 8; ++kt) {
      // stage(s+1) landed when <=2 vm loads outstanding (stages s+2 only)
      asm volatile("s_waitcnt vmcnt(2)" ::: "memory");
      __builtin_amdgcn_s_barrier();
      {
        const int j2  = j + ((kt + 3) >> 3);
        const int kt2 = (kt + 3) & 7;
        if (j2 < NJ) STAGE(j2, kt2, (kt + 3) & 3);
      }
      // prefetch frags(s+1) into the alternate reg buffer (garbage at last step, unused)
      {
        const unsigned char* sbn = &smem[(kt + 1) & 3][0];
#pragma unroll
        for (int s2 = 0; s2 < 2; ++s2)
#pragma unroll
          for (int n = 0; n < 2; ++n)
            bF[(kt + 1) & 1][s2][n] =
                *reinterpret_cast<const bf16x8s*>(sbn + offB[s2][n]);
      }
      asm volatile("s_waitcnt lgkmcnt(4)" ::: "memory");  // frags(s) ready
      __builtin_amdgcn_sched_barrier(0);
      __builtin_amdgcn_s_setprio(1);
#pragma unroll
      for (int s2 = 0; s2 < 2; ++s2)
#pragma unroll
        for (int m = 0; m < 2; ++m)
#pragma unroll
          for (int n = 0; n < 2; ++n)
            acc[m][n] = __builtin_amdgcn_mfma_f32_32x32x16_bf16(
                aF[m][kt * 2 + s2], bF[kt & 1][s2][n], acc[m][n], 0, 0, 0);
      __builtin_amdgcn_s_setprio(0);
      __builtin_amdgcn_sched_barrier(0);
    }

    // ---- per-tile epilogue: VALU only (exp partials in regs, no shuffles) ----
    // 32x32 C/D layout: col = lane&31, row = (reg&3) + 8*(reg>>2) + 4*(lane>>5)
#pragma unroll
    for (int m = 0; m < 2; ++m)
#pragma unroll
      for (int reg = 0; reg < 16; ++reg)
        rs[m][reg] += __expf(acc[m][0][reg] * TEMP_INV) +
                      __expf(acc[m][1][reg] * TEMP_INV);

    const bool diagT = (cg * NJ + j == (int)blockIdx.y);
    if (diagT && wr == wc) {
#pragma unroll
      for (int m = 0; m < 2; ++m)
#pragma unroll
        for (int reg = 0; reg < 16; ++reg) {
          const int crow = (reg & 3) + 8 * (reg >> 2) + 4 * g2;
          if (r32 == crow)
            diag[row0 + wr * 64 + m * 32 + crow] = acc[m][m][reg];
        }
    }
  }

  // ---- once per block: reduce over the 32 col-lanes, atomic into rowsum ----
#pragma unroll
  for (int m = 0; m < 2; ++m)
#pragma unroll
    for (int reg = 0; reg < 16; ++reg) {
      float s = rs[m][reg];
      s += __shfl_xor(s, 1, 64);
      s += __shfl_xor(s, 2, 64);
      s += __shfl_xor(s, 4, 64);
      s += __shfl_xor(s, 8, 64);
      s += __shfl_xor(s, 16, 64);
      if (r32 == 0)
        atomicAdd(&rowsum[row0 + wr * 64 + m * 32 + (reg & 3) + 8 * (reg >> 2) + 4 * g2], s);
    }
}

// ---- kernel 3: loss_i = log(rowsum_i) - diag_i*20; mean -> scalar -----------
__global__ __launch_bounds__(1024) void nce_finalize(const float* __restrict__ rowsum,
                                                     const float* __restrict__ diag,
                                                     float* __restrict__ out, int n) {
  __shared__ float red[16];
  float s = 0.0f;
  for (int i = threadIdx.x; i < n; i += 1024)
    s += logf(rowsum[i]) - diag[i] * TEMP_INV;
#pragma unroll
  for (int m = 1; m < 64; m <<= 1) s += __shfl_xor(s, m, 64);
  if ((threadIdx.x & 63) == 0) red[threadIdx.x >> 6] = s;
  __syncthreads();
  if (threadIdx.x == 0) {
    float t = 0.0f;
#pragma unroll
    for (int i = 0; i < 16; ++i) t += red[i];
    out[0] = t / (float)n;
  }
}

// ---- launch -----------------------------------------------------------------
extern "C" void kernel_launch(void* const* d_in, const int* in_sizes, int n_in,
                              void* d_out, int out_size, void* d_ws, size_t ws_size,
                              hipStream_t stream) {
  const float* anc = (const float*)d_in[0];
  const float* pos = (const float*)d_in[1];
  const float* neg = (const float*)d_in[2];
  const int B  = in_sizes[0] / D;   // 8192
  const int N2 = 2 * B;             // 16384

  char* ws = (char*)d_ws;
  unsigned short* An = (unsigned short*)ws;                          // B*D bf16
  unsigned short* Tn = (unsigned short*)(ws + (size_t)B * D * 2);    // 2B*D bf16
  float* rowsum = (float*)(ws + (size_t)B * D * 2 + (size_t)N2 * D * 2);
  float* diag   = rowsum + B;

  nce_normalize<<<3 * B / 16, 256, 0, stream>>>(anc, pos, neg, An, Tn, rowsum, B);

  dim3 grid(N2 / (NJ * 128), B / 128);   // (16, 64) = 1024 blocks = 4/CU
  nce_scores<<<grid, 256, 0, stream>>>(An, Tn, rowsum, diag);

  nce_finalize<<<1, 1024, 0, stream>>>(rowsum, diag, (float*)d_out, B);
}

// Round 7
// 192.304 us; speedup vs baseline: 1.5497x; 1.5497x over previous
//
#include <hip/hip_runtime.h>
#include <hip/hip_bf16.h>

#define D 256
#define TEMP_INV 20.0f   // 1 / 0.05
#define NJ 16            // 128-col tiles per colgroup (2048 cols per block)
#define NS (NJ * 8)      // K-steps per block (BK=32)

typedef __attribute__((ext_vector_type(8))) short bf16x8s;  // 8 bf16 in 4 VGPRs
typedef __attribute__((ext_vector_type(4))) float f32x4;

// ---- helpers ----------------------------------------------------------------
__device__ __forceinline__ unsigned short f2bf(float f) {
  unsigned u = __float_as_uint(f);
  unsigned r = u + 0x7FFFu + ((u >> 16) & 1u);
  return (unsigned short)(r >> 16);
}

__device__ __forceinline__ void gld16(const void* g, void* l) {
  // async global->LDS, 16B/lane; LDS dest is wave-uniform base + lane*16
  __builtin_amdgcn_global_load_lds(
      (const __attribute__((address_space(1))) void*)g,
      (__attribute__((address_space(3))) void*)l, 16, 0, 0);
}

// ---- kernel 1: fused row L2-normalize f32 -> bf16 (3 inputs) + zero scratch -
__global__ __launch_bounds__(256) void nce_normalize(const float* __restrict__ anc,
                                                     const float* __restrict__ pos,
                                                     const float* __restrict__ neg,
                                                     unsigned short* __restrict__ An,
                                                     unsigned short* __restrict__ Tn,
                                                     float* __restrict__ rowsum,
                                                     int* __restrict__ counter,
                                                     int B) {
  // first B/256 blocks zero rowsum; block 0 thread 0 zeroes the done-counter
  int zi = blockIdx.x * 256 + threadIdx.x;
  if (blockIdx.x < (B + 255) / 256 && zi < B) rowsum[zi] = 0.0f;
  if (blockIdx.x == 0 && threadIdx.x == 0) *counter = 0;

  const int lane = threadIdx.x & 63;
  const int wid  = threadIdx.x >> 6;
  const int sub  = lane >> 4, lr = lane & 15;
  int row = blockIdx.x * 16 + wid * 4 + sub;

  const float* src;
  unsigned short* dst;
  int r2;
  if (row < B)          { src = anc; dst = An; r2 = row; }
  else if (row < 2 * B) { src = pos; dst = Tn; r2 = row - B; }
  else                  { src = neg; dst = Tn + (size_t)B * D; r2 = row - 2 * B; }

  const float4* sp = reinterpret_cast<const float4*>(src) + (size_t)r2 * (D / 4);
  float4 v[4];
#pragma unroll
  for (int c = 0; c < 4; ++c) v[c] = sp[lr + c * 16];
  float ss = 0.0f;
#pragma unroll
  for (int c = 0; c < 4; ++c)
    ss += v[c].x * v[c].x + v[c].y * v[c].y + v[c].z * v[c].z + v[c].w * v[c].w;
  ss += __shfl_xor(ss, 1, 64);
  ss += __shfl_xor(ss, 2, 64);
  ss += __shfl_xor(ss, 4, 64);
  ss += __shfl_xor(ss, 8, 64);
  float inv = rsqrtf(fmaxf(ss, 1e-24f));
  ushort4* dp = reinterpret_cast<ushort4*>(dst) + (size_t)r2 * (D / 4);
#pragma unroll
  for (int c = 0; c < 4; ++c) {
    ushort4 o;
    o.x = f2bf(v[c].x * inv);
    o.y = f2bf(v[c].y * inv);
    o.z = f2bf(v[c].z * inv);
    o.w = f2bf(v[c].w * inv);
    dp[lr + c * 16] = o;
  }
}

// ---- kernel 2: A-in-registers MFMA GEMM, reg-prefetch pipeline + fused tail -
// R5-proven base (16x16x32, launch_bounds(256,2), 4-buffer ring, XOR swizzle
// with pre-swizzled global source, rule #21), plus:
//  * B-fragment register double-buffer: step s reads frags(s+1) while MFMAing
//    frags(s); wait is lgkmcnt(4) (previous step's 4 ds_reads), so ds latency
//    hides under MFMA.  Order per step:
//      vmcnt(2) -> s_barrier -> STAGE(s+3) -> ds_read frags(s+1)
//      -> lgkmcnt(4) + sched_barrier -> setprio(1) 16x MFMA setprio(0)
//    vmcnt(2) BEFORE the barrier proves stage(s+1) landed for all waves
//    (outstanding at that point: stage s+1, s+2 = 4 loads; wait <=2).
//    STAGE(s+3) overwrites buf(s-1); its readers (frags(s-1), read at step
//    s-2) drained at each wave's step s-1 lgkmcnt(4), before this barrier.
//  * finalize fused via last-block pattern (device atomics + threadfence).
__global__ __launch_bounds__(256, 2) void nce_scores(const unsigned short* __restrict__ A,
                                                     const unsigned short* __restrict__ T,
                                                     float* __restrict__ rowsum,
                                                     float* __restrict__ diag,
                                                     int* __restrict__ counter,
                                                     float* __restrict__ out,
                                                     int B, int nblocks) {
  __shared__ unsigned char smem[4][8192];   // B tile ring buffer
  __shared__ float red[4];
  __shared__ int lastFlag;

  const int tid  = threadIdx.x;
  const int lane = tid & 63;
  const int wid  = __builtin_amdgcn_readfirstlane(tid >> 6);
  const int wr = wid >> 1, wc = wid & 1;
  const int row0 = blockIdx.y * 128;
  const int cg   = blockIdx.x;              // colgroup: cols [cg*2048, +2048)
  const int r = lane & 15, g = lane >> 4;

  // ---- B staging: lane -> (R, C) via inverse swizzle ----
  // gload_lds writes lane i at base + i*16 => superrow S = slot*8 + (i>>3),
  // p' = i&7;  p = p' ^ (S&7) = (i&7)^(i>>3);  R = 2S + (p>>2);  C = p&3.
  const int pp    = (lane & 7) ^ (lane >> 3);
  const int Rbase = 2 * (lane >> 3) + (pp >> 2);
  const int Cb    = pp & 3;
  const unsigned char* gB = (const unsigned char*)T +
      (((size_t)(cg * 2048 + wid * 32 + Rbase)) << 9) + Cb * 16;

  auto STAGE = [&](int s) {                 // dst buffer = s & 3
    const unsigned char* gb = gB + (size_t)(s >> 3) * 65536 + (s & 7) * 64;
    unsigned char* sb = &smem[s & 3][0];
    gld16(gb,        sb + wid * 2048);           // rows [wid*32, +16)
    gld16(gb + 8192, sb + wid * 2048 + 1024);    // rows [wid*32+16, +16)
  };

  // ---- fragment read offsets (swizzled), within one 8KB buffer ----
  const int S7   = (r >> 1) & 7;
  const int pA   = (((r & 1) << 2) + g) ^ S7;
  const int offF = ((r >> 1) << 7) + (pA << 4);
  const int offB = wc * 4096 + offF;            // + n*1024 per fragment

  // ---- load the wave's whole A panel into registers (64 rows x 256 K) ----
  const unsigned short* aPtr = A + (size_t)(row0 + wr * 64 + r) * D + g * 8;
  bf16x8s aF[4][8];
#pragma unroll
  for (int m = 0; m < 4; ++m)
#pragma unroll
    for (int kt = 0; kt < 8; ++kt)
      aF[m][kt] = *reinterpret_cast<const bf16x8s*>(aPtr + (size_t)m * 16 * D + kt * 32);

  // prefetch depth 3 (6 gload_lds in flight)
  STAGE(0);
  STAGE(1);
  STAGE(2);

  float rs[4][4];
#pragma unroll
  for (int m = 0; m < 4; ++m)
#pragma unroll
    for (int reg = 0; reg < 4; ++reg) rs[m][reg] = 0.0f;

  bf16x8s bF[2][4];   // [regbuf][n] — indices compile-time everywhere

  // ---- prologue: wait stage(0) (aF loads are older, drain first), read frags(0)
  asm volatile("s_waitcnt vmcnt(4)" ::: "memory");
  __builtin_amdgcn_s_barrier();
  {
    const unsigned char* sb0 = &smem[0][0];
#pragma unroll
    for (int n = 0; n < 4; ++n)
      bF[0][n] = *reinterpret_cast<const bf16x8s*>(sb0 + offB + n * 1024);
  }

  for (int j = 0; j < NJ; ++j) {
    f32x4 acc[4][4];
#pragma unroll
    for (int m = 0; m < 4; ++m)
#pragma unroll
      for (int n = 0; n < 4; ++n) acc[m][n] = (f32x4)0.0f;

#pragma unroll
    for (int kt = 0; kt < 8; ++kt) {
      const int s = j * 8 + kt;
      // stage(s+1) landed when <=2 vm loads outstanding (only stage s+2 left)
      asm volatile("s_waitcnt vmcnt(2)" ::: "memory");
      __builtin_amdgcn_s_barrier();
      if (s + 3 < NS) STAGE(s + 3);
      // prefetch frags(s+1) into the alternate reg buffer (last step: unused garbage)
      {
        const unsigned char* sbn = &smem[(kt + 1) & 3][0];   // (s+1)&3 == (kt+1)&3
#pragma unroll
        for (int n = 0; n < 4; ++n)
          bF[(kt + 1) & 1][n] =
              *reinterpret_cast<const bf16x8s*>(sbn + offB + n * 1024);
      }
      asm volatile("s_waitcnt lgkmcnt(4)" ::: "memory");  // frags(s) ready
      __builtin_amdgcn_sched_barrier(0);
      __builtin_amdgcn_s_setprio(1);
#pragma unroll
      for (int m = 0; m < 4; ++m)
#pragma unroll
        for (int n = 0; n < 4; ++n)
          acc[m][n] = __builtin_amdgcn_mfma_f32_16x16x32_bf16(aF[m][kt], bF[kt & 1][n], acc[m][n], 0, 0, 0);
      __builtin_amdgcn_s_setprio(0);
      __builtin_amdgcn_sched_barrier(0);
    }

    // ---- per-tile epilogue: VALU only (exp partials in regs) ----
    // C/D layout: col = lane&15 (=r), row = g*4 + reg  [measured m89]
    const bool diagTile = (cg * NJ + j == (int)blockIdx.y);
#pragma unroll
    for (int m = 0; m < 4; ++m) {
#pragma unroll
      for (int reg = 0; reg < 4; ++reg) {
        float s = 0.0f;
#pragma unroll
        for (int n = 0; n < 4; ++n) s += __expf(acc[m][n][reg] * TEMP_INV);
        rs[m][reg] += s;
        // diagonal raw score: row==col when wr==wc, n==m, r==g*4+reg
        if (diagTile && wr == wc && r == g * 4 + reg)
          diag[row0 + wr * 64 + m * 16 + r] = acc[m][m][reg];
      }
    }
  }

  // ---- once per block: reduce 16-lane groups, atomic into global rowsum ----
#pragma unroll
  for (int m = 0; m < 4; ++m) {
#pragma unroll
    for (int reg = 0; reg < 4; ++reg) {
      float s = rs[m][reg];
      s += __shfl_xor(s, 1, 64);
      s += __shfl_xor(s, 2, 64);
      s += __shfl_xor(s, 4, 64);
      s += __shfl_xor(s, 8, 64);
      if (r == 0) atomicAdd(&rowsum[row0 + wr * 64 + m * 16 + g * 4 + reg], s);
    }
  }

  // ---- last-block finalize: loss = mean(log(rowsum) - diag*20) ----
  __threadfence();                           // release rowsum/diag
  if (tid == 0) lastFlag = (atomicAdd(counter, 1) == nblocks - 1);
  __syncthreads();
  if (lastFlag) {
    __threadfence();                         // acquire
    float s = 0.0f;
    for (int i = tid; i < B; i += 256)
      s += logf(rowsum[i]) - diag[i] * TEMP_INV;
#pragma unroll
    for (int m = 1; m < 64; m <<= 1) s += __shfl_xor(s, m, 64);
    if ((tid & 63) == 0) red[tid >> 6] = s;
    __syncthreads();
    if (tid == 0) out[0] = (red[0] + red[1] + red[2] + red[3]) / (float)B;
  }
}

// ---- launch -----------------------------------------------------------------
extern "C" void kernel_launch(void* const* d_in, const int* in_sizes, int n_in,
                              void* d_out, int out_size, void* d_ws, size_t ws_size,
                              hipStream_t stream) {
  const float* anc = (const float*)d_in[0];
  const float* pos = (const float*)d_in[1];
  const float* neg = (const float*)d_in[2];
  const int B  = in_sizes[0] / D;   // 8192
  const int N2 = 2 * B;             // 16384

  char* ws = (char*)d_ws;
  unsigned short* An = (unsigned short*)ws;                          // B*D bf16
  unsigned short* Tn = (unsigned short*)(ws + (size_t)B * D * 2);    // 2B*D bf16
  float* rowsum = (float*)(ws + (size_t)B * D * 2 + (size_t)N2 * D * 2);
  float* diag   = rowsum + B;
  int* counter  = (int*)(diag + B);

  nce_normalize<<<3 * B / 16, 256, 0, stream>>>(anc, pos, neg, An, Tn, rowsum, counter, B);

  dim3 grid(N2 / (NJ * 128), B / 128);   // (8, 64) = 512 blocks = 2/CU
  nce_scores<<<grid, 256, 0, stream>>>(An, Tn, rowsum, diag, counter,
                                       (float*)d_out, B, grid.x * grid.y);
}

// Round 8
// 139.171 us; speedup vs baseline: 2.1414x; 1.3818x over previous
//
#include <hip/hip_runtime.h>
#include <hip/hip_bf16.h>

#define D 256
#define TEMP_INV 20.0f        // 1 / 0.05
#define K_EXP2 28.85390081777927f   // 20 / ln(2): e^(20x) = 2^(K_EXP2*x)
#define NJ 16                 // 128-col tiles per colgroup (2048 cols per block)
#define NS (NJ * 4)           // K-steps per block (BK=64, K=256 -> 4 per j-tile)

typedef __attribute__((ext_vector_type(8))) short bf16x8s;  // 8 bf16 in 4 VGPRs
typedef __attribute__((ext_vector_type(4))) float f32x4;

// ---- helpers ----------------------------------------------------------------
__device__ __forceinline__ unsigned short f2bf(float f) {
  unsigned u = __float_as_uint(f);
  unsigned r = u + 0x7FFFu + ((u >> 16) & 1u);
  return (unsigned short)(r >> 16);
}

__device__ __forceinline__ void gld16(const void* g, void* l) {
  // async global->LDS, 16B/lane; LDS dest is wave-uniform base + lane*16
  __builtin_amdgcn_global_load_lds(
      (const __attribute__((address_space(1))) void*)g,
      (__attribute__((address_space(3))) void*)l, 16, 0, 0);
}

// ---- kernel 1: fused row L2-normalize f32 -> bf16 (3 inputs) + zero rowsum --
__global__ __launch_bounds__(256) void nce_normalize(const float* __restrict__ anc,
                                                     const float* __restrict__ pos,
                                                     const float* __restrict__ neg,
                                                     unsigned short* __restrict__ An,
                                                     unsigned short* __restrict__ Tn,
                                                     float* __restrict__ rowsum,
                                                     int B) {
  int zi = blockIdx.x * 256 + threadIdx.x;
  if (blockIdx.x < (B + 255) / 256 && zi < B) rowsum[zi] = 0.0f;

  const int lane = threadIdx.x & 63;
  const int wid  = threadIdx.x >> 6;
  const int sub  = lane >> 4, lr = lane & 15;
  int row = blockIdx.x * 16 + wid * 4 + sub;

  const float* src;
  unsigned short* dst;
  int r2;
  if (row < B)          { src = anc; dst = An; r2 = row; }
  else if (row < 2 * B) { src = pos; dst = Tn; r2 = row - B; }
  else                  { src = neg; dst = Tn + (size_t)B * D; r2 = row - 2 * B; }

  const float4* sp = reinterpret_cast<const float4*>(src) + (size_t)r2 * (D / 4);
  float4 v[4];
#pragma unroll
  for (int c = 0; c < 4; ++c) v[c] = sp[lr + c * 16];
  float ss = 0.0f;
#pragma unroll
  for (int c = 0; c < 4; ++c)
    ss += v[c].x * v[c].x + v[c].y * v[c].y + v[c].z * v[c].z + v[c].w * v[c].w;
  ss += __shfl_xor(ss, 1, 64);
  ss += __shfl_xor(ss, 2, 64);
  ss += __shfl_xor(ss, 4, 64);
  ss += __shfl_xor(ss, 8, 64);
  float inv = rsqrtf(fmaxf(ss, 1e-24f));
  ushort4* dp = reinterpret_cast<ushort4*>(dst) + (size_t)r2 * (D / 4);
#pragma unroll
  for (int c = 0; c < 4; ++c) {
    ushort4 o;
    o.x = f2bf(v[c].x * inv);
    o.y = f2bf(v[c].y * inv);
    o.z = f2bf(v[c].z * inv);
    o.w = f2bf(v[c].w * inv);
    dp[lr + c * 16] = o;
  }
}

// ---- kernel 2: A-in-registers MFMA GEMM, BK=64, R5-proven sync skeleton -----
// Block: 128 rows x 2048 cols (NJ=16 j-tiles), K=256. 4 waves as 2x2; wave
// tile 64x64 via 4x4 16x16x32 MFMAs. A panel (64x256) in VGPRs. B streams
// through a 4-buffer LDS ring (4x16KB = 64KB); BK=64 -> 64 K-steps, each:
//   vmcnt(8) -> s_barrier -> 8x ds_read_b128 -> STAGE(s+3)
//   -> lgkmcnt(0) + sched_barrier -> setprio(1) 32x MFMA setprio(0) -> sched_barrier
// (exact R5 ordering, 2x work per step to amortize barrier + lgkm drain).
// vmcnt(8): outstanding at step top = stages s,s+1,s+2 (12 loads); wait <=8
// proves stage(s) landed. STAGE(s+3) overwrites buf(s-1), whose readers
// drained at their step s-1 lgkmcnt(0), before this step's barrier.
// LDS swizzle (128B rows, 8x16B chunks): logical chunk c stored at c^(R&7);
// staging inverse on the GLOBAL source address (rule #21): lane i covers
// row +(i>>3), source chunk (i&7)^(i>>3). Read lanes r=0..7 hit all 8 chunk
// slots; r=8..15 repeat -> 2-way = free [m136].
__global__ __launch_bounds__(256, 2) void nce_scores(const unsigned short* __restrict__ A,
                                                     const unsigned short* __restrict__ T,
                                                     float* __restrict__ rowsum,
                                                     float* __restrict__ diag) {
  __shared__ unsigned char smem[4][16384];   // B tile ring (BK=64)

  const int tid  = threadIdx.x;
  const int lane = tid & 63;
  const int wid  = __builtin_amdgcn_readfirstlane(tid >> 6);
  const int wr = wid >> 1, wc = wid & 1;
  const int row0 = blockIdx.y * 128;
  const int cg   = blockIdx.x;              // colgroup: cols [cg*2048, +2048)
  const int r = lane & 15, g = lane >> 4;

  // ---- staging source address (inverse swizzle) ----
  const int Rl = lane >> 3;                 // row within 8-row group
  const int Cl = (lane & 7) ^ Rl;           // source chunk
  const unsigned char* gB = (const unsigned char*)T +
      (((size_t)(cg * 2048 + wid * 32 + Rl)) << 9) + Cl * 16;

  auto STAGE = [&](int s) {                 // dst buffer = s & 3
    const unsigned char* gb = gB + (size_t)(s >> 2) * 65536 + (s & 3) * 128;
    unsigned char* sb = &smem[s & 3][0];
#pragma unroll
    for (int q = 0; q < 4; ++q)             // rows [wid*32+q*8, +8)
      gld16(gb + q * 4096, sb + wid * 4096 + q * 1024);
  };

  // ---- fragment read offsets (swizzled), within one 16KB buffer ----
  // frag (ks,n): row R = wc*64 + n*16 + r; chunk (ks*4+g)^(r&7)
  const int rx = r & 7;
  int offB[2][4];
#pragma unroll
  for (int ks = 0; ks < 2; ++ks)
#pragma unroll
    for (int n = 0; n < 4; ++n)
      offB[ks][n] = wc * 8192 + n * 2048 + r * 128 + ((((ks << 2) | g) ^ rx) << 4);

  // ---- load the wave's whole A panel into registers (64 rows x 256 K) ----
  const unsigned short* aPtr = A + (size_t)(row0 + wr * 64 + r) * D + g * 8;
  bf16x8s aF[4][8];
#pragma unroll
  for (int m = 0; m < 4; ++m)
#pragma unroll
    for (int t = 0; t < 8; ++t)
      aF[m][t] = *reinterpret_cast<const bf16x8s*>(aPtr + (size_t)m * 16 * D + t * 32);
  __builtin_amdgcn_sched_barrier(0);        // keep aF issues before STAGE issues

  // prefetch depth 3 (12 gload_lds in flight)
  STAGE(0);
  STAGE(1);
  STAGE(2);

  float rs[4][4];
#pragma unroll
  for (int m = 0; m < 4; ++m)
#pragma unroll
    for (int reg = 0; reg < 4; ++reg) rs[m][reg] = 0.0f;

  for (int j = 0; j < NJ; ++j) {
    f32x4 acc[4][4];
#pragma unroll
    for (int m = 0; m < 4; ++m)
#pragma unroll
      for (int n = 0; n < 4; ++n) acc[m][n] = (f32x4)0.0f;

#pragma unroll
    for (int kt = 0; kt < 4; ++kt) {
      const int s = j * 4 + kt;             // s & 3 == kt (compile-time buf idx)
      asm volatile("s_waitcnt vmcnt(8)" ::: "memory");
      __builtin_amdgcn_s_barrier();
      const unsigned char* sb = &smem[kt][0];
      bf16x8s bF[2][4];
#pragma unroll
      for (int ks = 0; ks < 2; ++ks)
#pragma unroll
        for (int n = 0; n < 4; ++n)
          bF[ks][n] = *reinterpret_cast<const bf16x8s*>(sb + offB[ks][n]);
      if (s + 3 < NS) STAGE(s + 3);
      asm volatile("s_waitcnt lgkmcnt(0)" ::: "memory");
      __builtin_amdgcn_sched_barrier(0);
      __builtin_amdgcn_s_setprio(1);
#pragma unroll
      for (int ks = 0; ks < 2; ++ks)
#pragma unroll
        for (int m = 0; m < 4; ++m)
#pragma unroll
          for (int n = 0; n < 4; ++n)
            acc[m][n] = __builtin_amdgcn_mfma_f32_16x16x32_bf16(
                aF[m][kt * 2 + ks], bF[ks][n], acc[m][n], 0, 0, 0);
      __builtin_amdgcn_s_setprio(0);
      __builtin_amdgcn_sched_barrier(0);
    }

    // ---- per-tile epilogue: VALU only (exp partials in regs) ----
    // C/D layout: col = lane&15 (=r), row = g*4 + reg  [measured m89]
    const bool diagTile = (cg * NJ + j == (int)blockIdx.y);
#pragma unroll
    for (int m = 0; m < 4; ++m) {
#pragma unroll
      for (int reg = 0; reg < 4; ++reg) {
        float s = 0.0f;
#pragma unroll
        for (int n = 0; n < 4; ++n)
          s += __builtin_amdgcn_exp2f(acc[m][n][reg] * K_EXP2);   // e^(20*score)
        rs[m][reg] += s;
        // diagonal raw score: row==col when wr==wc, n==m, r==g*4+reg
        if (diagTile && wr == wc && r == g * 4 + reg)
          diag[row0 + wr * 64 + m * 16 + r] = acc[m][m][reg];
      }
    }
  }

  // ---- once per block: reduce 16-lane groups, atomic into global rowsum ----
#pragma unroll
  for (int m = 0; m < 4; ++m) {
#pragma unroll
    for (int reg = 0; reg < 4; ++reg) {
      float s = rs[m][reg];
      s += __shfl_xor(s, 1, 64);
      s += __shfl_xor(s, 2, 64);
      s += __shfl_xor(s, 4, 64);
      s += __shfl_xor(s, 8, 64);
      if (r == 0) atomicAdd(&rowsum[row0 + wr * 64 + m * 16 + g * 4 + reg], s);
    }
  }
}

// ---- kernel 3: loss_i = log(rowsum_i) - diag_i*20; mean -> scalar -----------
__global__ __launch_bounds__(1024) void nce_finalize(const float* __restrict__ rowsum,
                                                     const float* __restrict__ diag,
                                                     float* __restrict__ out, int n) {
  __shared__ float red[16];
  float s = 0.0f;
  for (int i = threadIdx.x; i < n; i += 1024)
    s += logf(rowsum[i]) - diag[i] * TEMP_INV;
#pragma unroll
  for (int m = 1; m < 64; m <<= 1) s += __shfl_xor(s, m, 64);
  if ((threadIdx.x & 63) == 0) red[threadIdx.x >> 6] = s;
  __syncthreads();
  if (threadIdx.x == 0) {
    float t = 0.0f;
#pragma unroll
    for (int i = 0; i < 16; ++i) t += red[i];
    out[0] = t / (float)n;
  }
}

// ---- launch -----------------------------------------------------------------
extern "C" void kernel_launch(void* const* d_in, const int* in_sizes, int n_in,
                              void* d_out, int out_size, void* d_ws, size_t ws_size,
                              hipStream_t stream) {
  const float* anc = (const float*)d_in[0];
  const float* pos = (const float*)d_in[1];
  const float* neg = (const float*)d_in[2];
  const int B  = in_sizes[0] / D;   // 8192
  const int N2 = 2 * B;             // 16384

  char* ws = (char*)d_ws;
  unsigned short* An = (unsigned short*)ws;                          // B*D bf16
  unsigned short* Tn = (unsigned short*)(ws + (size_t)B * D * 2);    // 2B*D bf16
  float* rowsum = (float*)(ws + (size_t)B * D * 2 + (size_t)N2 * D * 2);
  float* diag   = rowsum + B;

  nce_normalize<<<3 * B / 16, 256, 0, stream>>>(anc, pos, neg, An, Tn, rowsum, B);

  dim3 grid(N2 / (NJ * 128), B / 128);   // (8, 64) = 512 blocks = 2/CU
  nce_scores<<<grid, 256, 0, stream>>>(An, Tn, rowsum, diag);

  nce_finalize<<<1, 1024, 0, stream>>>(rowsum, diag, (float*)d_out, B);
}